// Round 1
// baseline (986.519 us; speedup 1.0000x reference)
//
#include <hip/hip_runtime.h>

#define N_NODES 50000
#define N_EDGES 800000

// ---------------- Layer 1: aggregate raw x (2 feats/edge) ----------------
__global__ void scatter1(const int* __restrict__ src, const int* __restrict__ dst,
                         const float* __restrict__ ew, const float* __restrict__ x,
                         float* __restrict__ agg1) {
    int e = blockIdx.x * blockDim.x + threadIdx.x;
    if (e >= N_EDGES) return;
    int s = src[e];
    int d = dst[e];
    float w = ew[e];
    float2 xv = ((const float2*)x)[s];
    atomicAdd(&agg1[2 * d],     w * xv.x);
    atomicAdd(&agg1[2 * d + 1], w * xv.y);
}

// h1[i][f] = relu(agg1[i][0]*W1[0][f] + agg1[i][1]*W1[1][f] + b1[f])
__global__ void dense1(const float* __restrict__ agg1, const float* __restrict__ W1,
                       const float* __restrict__ b1, float* __restrict__ h1) {
    int tid = blockIdx.x * blockDim.x + threadIdx.x;
    if (tid >= N_NODES * 128) return;
    int i = tid >> 7;
    int f = tid & 127;
    float a0 = agg1[2 * i];
    float a1 = agg1[2 * i + 1];
    float v = fmaf(a0, W1[f], fmaf(a1, W1[128 + f], b1[f]));
    h1[tid] = fmaxf(v, 0.0f);
}

// ---------------- Layer 2: project first (128->64), then aggregate --------
// t2 = h1 @ W2   (no bias here; b2 is added post-aggregation)
__global__ void gemm2(const float* __restrict__ h1, const float* __restrict__ W2,
                      float* __restrict__ t2) {
    __shared__ float w2s[128 * 64];  // 32 KB
    for (int k = threadIdx.x; k < 128 * 64; k += blockDim.x) w2s[k] = W2[k];
    __syncthreads();
    // 256 threads = 4 nodes per block, one out-feature per lane
    int node = blockIdx.x * 4 + (threadIdx.x >> 6);
    int f = threadIdx.x & 63;
    if (node >= N_NODES) return;
    const float* hr = h1 + node * 128;
    float acc = 0.0f;
#pragma unroll 8
    for (int k = 0; k < 128; k++) {
        acc = fmaf(hr[k], w2s[k * 64 + f], acc);  // hr[k]: wave-broadcast load
    }
    t2[node * 64 + f] = acc;
}

// agg2[dst] += ew * t2[src] : 16 lanes/edge, float4 gather + 4 atomics each
__global__ void scatter2(const int* __restrict__ src, const int* __restrict__ dst,
                         const float* __restrict__ ew, const float* __restrict__ t2,
                         float* __restrict__ agg2) {
    int tid = blockIdx.x * blockDim.x + threadIdx.x;
    if (tid >= N_EDGES * 16) return;
    int e = tid >> 4;
    int g = tid & 15;
    int s = src[e];
    int d = dst[e];
    float w = ew[e];
    float4 v = ((const float4*)(t2 + s * 64))[g];
    float* o = agg2 + d * 64 + g * 4;
    atomicAdd(o,     w * v.x);
    atomicAdd(o + 1, w * v.y);
    atomicAdd(o + 2, w * v.z);
    atomicAdd(o + 3, w * v.w);
}

// ---------------- Layer 3: fuse relu(agg2+b2) with the 64->1 projection ---
// t3[i] = sum_f relu(agg2[i][f]+b2[f]) * W3[f]   (wave per node)
__global__ void relu_dot3(const float* __restrict__ agg2, const float* __restrict__ b2,
                          const float* __restrict__ W3, float* __restrict__ t3) {
    int gtid = blockIdx.x * blockDim.x + threadIdx.x;
    int node = gtid >> 6;
    int lane = threadIdx.x & 63;
    if (node >= N_NODES) return;
    float v = fmaxf(agg2[node * 64 + lane] + b2[lane], 0.0f) * W3[lane];
#pragma unroll
    for (int off = 32; off > 0; off >>= 1) v += __shfl_down(v, off);
    if (lane == 0) t3[node] = v;
}

__global__ void init_out(float* __restrict__ out, const float* __restrict__ b3) {
    int i = blockIdx.x * blockDim.x + threadIdx.x;
    if (i < N_NODES) out[i] = b3[0];
}

__global__ void scatter3(const int* __restrict__ src, const int* __restrict__ dst,
                         const float* __restrict__ ew, const float* __restrict__ t3,
                         float* __restrict__ out) {
    int e = blockIdx.x * blockDim.x + threadIdx.x;
    if (e >= N_EDGES) return;
    atomicAdd(&out[dst[e]], ew[e] * t3[src[e]]);
}

extern "C" void kernel_launch(void* const* d_in, const int* in_sizes, int n_in,
                              void* d_out, int out_size, void* d_ws, size_t ws_size,
                              hipStream_t stream) {
    const float* x  = (const float*)d_in[0];
    const int*   ei = (const int*)d_in[1];     // [2, E] row-major
    const float* ew = (const float*)d_in[2];
    const float* W1 = (const float*)d_in[3];
    const float* b1 = (const float*)d_in[4];
    const float* W2 = (const float*)d_in[5];
    const float* b2 = (const float*)d_in[6];
    const float* W3 = (const float*)d_in[7];
    const float* b3 = (const float*)d_in[8];
    float* out = (float*)d_out;

    const int* src = ei;
    const int* dst = ei + N_EDGES;

    // workspace layout (floats)
    float* ws   = (float*)d_ws;
    float* agg1 = ws;                       // 100000
    float* h1   = agg1 + 100000;            // 6,400,000
    float* t2   = h1 + 6400000;             // 3,200,000
    float* agg2 = t2 + 3200000;             // 3,200,000
    float* t3   = agg2 + 3200000;           // 50,000

    hipMemsetAsync(agg1, 0, 100000 * sizeof(float), stream);
    hipMemsetAsync(agg2, 0, 3200000 * sizeof(float), stream);

    // Layer 1
    scatter1<<<(N_EDGES + 255) / 256, 256, 0, stream>>>(src, dst, ew, x, agg1);
    dense1<<<(N_NODES * 128 + 255) / 256, 256, 0, stream>>>(agg1, W1, b1, h1);

    // Layer 2
    gemm2<<<(N_NODES + 3) / 4, 256, 0, stream>>>(h1, W2, t2);
    scatter2<<<(N_EDGES * 16 + 255) / 256, 256, 0, stream>>>(src, dst, ew, t2, agg2);

    // Layer 3
    relu_dot3<<<(N_NODES * 64 + 255) / 256, 256, 0, stream>>>(agg2, b2, W3, t3);
    init_out<<<(N_NODES + 255) / 256, 256, 0, stream>>>(out, b3);
    scatter3<<<(N_EDGES + 255) / 256, 256, 0, stream>>>(src, dst, ew, t3, out);
}

// Round 2
// 482.110 us; speedup vs baseline: 2.0463x; 2.0463x over previous
//
#include <hip/hip_runtime.h>

#define N_NODES 50000
#define N_EDGES 800000

// ================= CSR build (counting sort by dst) =================
__global__ void hist_kernel(const int* __restrict__ dst, int* __restrict__ hist) {
    int e = blockIdx.x * blockDim.x + threadIdx.x;
    if (e < N_EDGES) atomicAdd(&hist[dst[e]], 1);
}

// Single-block exclusive scan over 50000 counts -> row_ptr[N+1], cursor[N]
__global__ void scan_kernel(const int* __restrict__ hist, int* __restrict__ row_ptr,
                            int* __restrict__ cursor) {
    __shared__ int lds[1024];
    const int CH = (N_NODES + 1023) / 1024;  // 49
    int t = threadIdx.x;
    int base = t * CH;
    int s = 0;
    for (int j = 0; j < CH; j++) {
        int idx = base + j;
        if (idx < N_NODES) s += hist[idx];
    }
    lds[t] = s;
    __syncthreads();
    // Hillis-Steele inclusive scan over 1024 partials
    for (int off = 1; off < 1024; off <<= 1) {
        int v = (t >= off) ? lds[t - off] : 0;
        __syncthreads();
        lds[t] += v;
        __syncthreads();
    }
    int run = (t == 0) ? 0 : lds[t - 1];
    for (int j = 0; j < CH; j++) {
        int idx = base + j;
        if (idx < N_NODES) {
            row_ptr[idx] = run;
            cursor[idx] = run;
            run += hist[idx];
        }
    }
    if (t == 1023) row_ptr[N_NODES] = lds[1023];
}

// sorted[pos] = {src, bits(w)} bucketed by dst
__global__ void scatter_edges(const int* __restrict__ src, const int* __restrict__ dst,
                              const float* __restrict__ ew, int* __restrict__ cursor,
                              int2* __restrict__ sorted) {
    int e = blockIdx.x * blockDim.x + threadIdx.x;
    if (e >= N_EDGES) return;
    int d = dst[e];
    int pos = atomicAdd(&cursor[d], 1);
    sorted[pos] = make_int2(src[e], __float_as_int(ew[e]));
}

// ================= Layer 1: gather raw x (2 feats), then dense ======
__global__ void gather1(const int* __restrict__ row_ptr, const int2* __restrict__ sorted,
                        const float* __restrict__ x, float* __restrict__ agg1) {
    int i = blockIdx.x * blockDim.x + threadIdx.x;
    if (i >= N_NODES) return;
    int beg = row_ptr[i], end = row_ptr[i + 1];
    float a0 = 0.f, a1 = 0.f;
    for (int e = beg; e < end; e++) {
        int2 p = sorted[e];
        float w = __int_as_float(p.y);
        float2 xv = ((const float2*)x)[p.x];
        a0 = fmaf(w, xv.x, a0);
        a1 = fmaf(w, xv.y, a1);
    }
    agg1[2 * i] = a0;
    agg1[2 * i + 1] = a1;
}

__global__ void dense1(const float* __restrict__ agg1, const float* __restrict__ W1,
                       const float* __restrict__ b1, float* __restrict__ h1) {
    int tid = blockIdx.x * blockDim.x + threadIdx.x;
    if (tid >= N_NODES * 128) return;
    int i = tid >> 7;
    int f = tid & 127;
    float a0 = agg1[2 * i];
    float a1 = agg1[2 * i + 1];
    float v = fmaf(a0, W1[f], fmaf(a1, W1[128 + f], b1[f]));
    h1[tid] = fmaxf(v, 0.0f);
}

// ================= Layer 2: project (128->64), gather, fuse layer-3 dot ==
__global__ void gemm2(const float* __restrict__ h1, const float* __restrict__ W2,
                      float* __restrict__ t2) {
    __shared__ float w2s[128 * 64];  // 32 KB
    for (int k = threadIdx.x; k < 128 * 64; k += blockDim.x) w2s[k] = W2[k];
    __syncthreads();
    int node = blockIdx.x * 4 + (threadIdx.x >> 6);
    int f = threadIdx.x & 63;
    if (node >= N_NODES) return;
    const float* hr = h1 + node * 128;
    float acc = 0.0f;
#pragma unroll 8
    for (int k = 0; k < 128; k++) acc = fmaf(hr[k], w2s[k * 64 + f], acc);
    t2[node * 64 + f] = acc;
}

// Per node: wave of 64 lanes (lane = feature). acc = sum_e w_e * t2[src_e][lane];
// h2 = relu(acc + b2); t3[node] = sum_lane h2 * W3[lane].  No agg2 materialized.
__global__ void gather2_dot3(const int* __restrict__ row_ptr, const int2* __restrict__ sorted,
                             const float* __restrict__ t2, const float* __restrict__ b2,
                             const float* __restrict__ W3, float* __restrict__ t3) {
    int gtid = blockIdx.x * blockDim.x + threadIdx.x;
    int node = gtid >> 6;
    int lane = threadIdx.x & 63;
    if (node >= N_NODES) return;
    int beg = row_ptr[node], end = row_ptr[node + 1];
    float acc = 0.f;
    int e = beg;
    // unroll by 2 for load pipelining
    for (; e + 1 < end; e += 2) {
        int2 p0 = sorted[e];
        int2 p1 = sorted[e + 1];
        float v0 = t2[p0.x * 64 + lane];
        float v1 = t2[p1.x * 64 + lane];
        acc = fmaf(__int_as_float(p0.y), v0, acc);
        acc = fmaf(__int_as_float(p1.y), v1, acc);
    }
    if (e < end) {
        int2 p = sorted[e];
        acc = fmaf(__int_as_float(p.y), t2[p.x * 64 + lane], acc);
    }
    float h = fmaxf(acc + b2[lane], 0.f) * W3[lane];
#pragma unroll
    for (int off = 32; off; off >>= 1) h += __shfl_down(h, off);
    if (lane == 0) t3[node] = h;
}

// ================= Layer 3: gather scalar t3 ========================
__global__ void gather3(const int* __restrict__ row_ptr, const int2* __restrict__ sorted,
                        const float* __restrict__ t3, const float* __restrict__ b3,
                        float* __restrict__ out) {
    int i = blockIdx.x * blockDim.x + threadIdx.x;
    if (i >= N_NODES) return;
    int beg = row_ptr[i], end = row_ptr[i + 1];
    float acc = 0.f;
    for (int e = beg; e < end; e++) {
        int2 p = sorted[e];
        acc = fmaf(__int_as_float(p.y), t3[p.x], acc);
    }
    out[i] = acc + b3[0];
}

extern "C" void kernel_launch(void* const* d_in, const int* in_sizes, int n_in,
                              void* d_out, int out_size, void* d_ws, size_t ws_size,
                              hipStream_t stream) {
    const float* x  = (const float*)d_in[0];
    const int*   ei = (const int*)d_in[1];     // [2, E]
    const float* ew = (const float*)d_in[2];
    const float* W1 = (const float*)d_in[3];
    const float* b1 = (const float*)d_in[4];
    const float* W2 = (const float*)d_in[5];
    const float* b2 = (const float*)d_in[6];
    const float* W3 = (const float*)d_in[7];
    const float* b3 = (const float*)d_in[8];
    float* out = (float*)d_out;

    const int* src = ei;
    const int* dst = ei + N_EDGES;

    // workspace layout
    char* p = (char*)d_ws;
    int*  hist    = (int*)p;            p += N_NODES * sizeof(int);
    int*  row_ptr = (int*)p;            p += (N_NODES + 1) * sizeof(int);
    int*  cursor  = (int*)p;            p += N_NODES * sizeof(int);
    p = (char*)(((uintptr_t)p + 15) & ~(uintptr_t)15);
    int2* sorted  = (int2*)p;           p += N_EDGES * sizeof(int2);      // 6.4 MB
    float* agg1   = (float*)p;          p += 2 * N_NODES * sizeof(float);
    float* h1     = (float*)p;          p += 128 * N_NODES * sizeof(float); // 25.6 MB
    float* t2     = (float*)p;          p += 64 * N_NODES * sizeof(float);  // 12.8 MB
    float* t3     = (float*)p;          p += N_NODES * sizeof(float);

    hipMemsetAsync(hist, 0, N_NODES * sizeof(int), stream);

    // CSR build
    hist_kernel<<<(N_EDGES + 255) / 256, 256, 0, stream>>>(dst, hist);
    scan_kernel<<<1, 1024, 0, stream>>>(hist, row_ptr, cursor);
    scatter_edges<<<(N_EDGES + 255) / 256, 256, 0, stream>>>(src, dst, ew, cursor, sorted);

    // Layer 1
    gather1<<<(N_NODES + 255) / 256, 256, 0, stream>>>(row_ptr, sorted, x, agg1);
    dense1<<<(N_NODES * 128 + 255) / 256, 256, 0, stream>>>(agg1, W1, b1, h1);

    // Layer 2 (+ fused layer-3 projection)
    gemm2<<<(N_NODES + 3) / 4, 256, 0, stream>>>(h1, W2, t2);
    gather2_dot3<<<(N_NODES * 64 + 255) / 256, 256, 0, stream>>>(row_ptr, sorted, t2, b2, W3, t3);

    // Layer 3
    gather3<<<(N_NODES + 255) / 256, 256, 0, stream>>>(row_ptr, sorted, t3, b3, out);
}

// Round 3
// 289.253 us; speedup vs baseline: 3.4106x; 1.6667x over previous
//
#include <hip/hip_runtime.h>

#define N_NODES 50000
#define N_EDGES 800000
#define SCAN_BLOCK 256
#define SCAN_NB ((N_NODES + SCAN_BLOCK - 1) / SCAN_BLOCK)  // 196

// ================= CSR build (counting sort by dst) =================
__global__ void hist_kernel(const int* __restrict__ dst, int* __restrict__ hist) {
    int e = blockIdx.x * blockDim.x + threadIdx.x;
    if (e < N_EDGES) atomicAdd(&hist[dst[e]], 1);
}

// Per-block inclusive scan of 256 hist entries; write block-local inclusive + block sums
__global__ void scan_block_kernel(const int* __restrict__ hist, int* __restrict__ incl,
                                  int* __restrict__ bsum) {
    __shared__ int lds[SCAN_BLOCK];
    int t = threadIdx.x;
    int i = blockIdx.x * SCAN_BLOCK + t;
    int v = (i < N_NODES) ? hist[i] : 0;
    lds[t] = v;
    __syncthreads();
    for (int off = 1; off < SCAN_BLOCK; off <<= 1) {
        int u = (t >= off) ? lds[t - off] : 0;
        __syncthreads();
        lds[t] += u;
        __syncthreads();
    }
    if (i < N_NODES) incl[i] = lds[t];
    if (t == SCAN_BLOCK - 1) bsum[blockIdx.x] = lds[t];
}

// Exclusive scan of the 196 block sums (single block)
__global__ void scan_top_kernel(int* __restrict__ bsum) {
    __shared__ int lds[SCAN_BLOCK];
    int t = threadIdx.x;
    int v = (t < SCAN_NB) ? bsum[t] : 0;
    lds[t] = v;
    __syncthreads();
    for (int off = 1; off < SCAN_BLOCK; off <<= 1) {
        int u = (t >= off) ? lds[t - off] : 0;
        __syncthreads();
        lds[t] += u;
        __syncthreads();
    }
    if (t < SCAN_NB) bsum[t] = lds[t] - v;  // exclusive
}

// row_ptr[i] = cursor[i] = block_offset + local_inclusive - hist[i]
__global__ void scan_finish_kernel(const int* __restrict__ hist, const int* __restrict__ incl,
                                   const int* __restrict__ bsum, int* __restrict__ row_ptr,
                                   int* __restrict__ cursor) {
    int i = blockIdx.x * SCAN_BLOCK + threadIdx.x;
    if (i == 0) row_ptr[N_NODES] = N_EDGES;
    if (i < N_NODES) {
        int ex = bsum[blockIdx.x] + incl[i] - hist[i];
        row_ptr[i] = ex;
        cursor[i] = ex;
    }
}

// sorted[pos] = {src, bits(w)} bucketed by dst
__global__ void scatter_edges(const int* __restrict__ src, const int* __restrict__ dst,
                              const float* __restrict__ ew, int* __restrict__ cursor,
                              int2* __restrict__ sorted) {
    int e = blockIdx.x * blockDim.x + threadIdx.x;
    if (e >= N_EDGES) return;
    int d = dst[e];
    int pos = atomicAdd(&cursor[d], 1);
    sorted[pos] = make_int2(src[e], __float_as_int(ew[e]));
}

// ====== Fused layer 1: gather x -> (a0,a1) -> h1 = relu(. @ W1 + b1) -> t2 = h1 @ W2 ======
// One wave per node (iterated 8x per wave); W1/b1/W2 staged in LDS.
#define L1_WAVES 4
#define L1_NPW 8
#define L1_NODES_PER_BLOCK (L1_WAVES * L1_NPW)  // 32
__global__ void fused_l1(const int* __restrict__ row_ptr, const int2* __restrict__ sorted,
                         const float* __restrict__ x, const float* __restrict__ W1,
                         const float* __restrict__ b1, const float* __restrict__ W2,
                         float* __restrict__ t2) {
    __shared__ float w2s[128 * 64];          // 32 KB
    __shared__ float w1s[256];
    __shared__ float b1s[128];
    __shared__ float hls[L1_WAVES][128];
    for (int k = threadIdx.x; k < 128 * 64; k += 256) w2s[k] = W2[k];
    w1s[threadIdx.x] = W1[threadIdx.x];      // 256 elements, block = 256
    if (threadIdx.x < 128) b1s[threadIdx.x] = b1[threadIdx.x];
    __syncthreads();
    int wave = threadIdx.x >> 6;
    int lane = threadIdx.x & 63;
    for (int it = 0; it < L1_NPW; it++) {
        int node = blockIdx.x * L1_NODES_PER_BLOCK + wave * L1_NPW + it;
        float a0 = 0.f, a1 = 0.f;
        if (node < N_NODES) {
            int beg = row_ptr[node], end = row_ptr[node + 1];
            for (int e = beg + lane; e < end; e += 64) {
                int2 p = sorted[e];
                float w = __int_as_float(p.y);
                float2 xv = ((const float2*)x)[p.x];
                a0 = fmaf(w, xv.x, a0);
                a1 = fmaf(w, xv.y, a1);
            }
        }
#pragma unroll
        for (int off = 32; off; off >>= 1) {
            a0 += __shfl_xor(a0, off);
            a1 += __shfl_xor(a1, off);
        }
        // h1 features lane and lane+64
        float hlo = fmaxf(fmaf(a0, w1s[lane],      fmaf(a1, w1s[128 + lane],      b1s[lane])),      0.f);
        float hhi = fmaxf(fmaf(a0, w1s[64 + lane], fmaf(a1, w1s[192 + lane],      b1s[64 + lane])), 0.f);
        hls[wave][lane] = hlo;
        hls[wave][lane + 64] = hhi;
        __syncthreads();
        float acc = 0.f;
#pragma unroll 8
        for (int k = 0; k < 128; k++) acc = fmaf(hls[wave][k], w2s[k * 64 + lane], acc);
        if (node < N_NODES) t2[node * 64 + lane] = acc;
        __syncthreads();
    }
}

// ====== Layer 2 gather + fused layer-3 projection (wave per node) ======
__global__ void gather2_dot3(const int* __restrict__ row_ptr, const int2* __restrict__ sorted,
                             const float* __restrict__ t2, const float* __restrict__ b2,
                             const float* __restrict__ W3, float* __restrict__ t3) {
    int gtid = blockIdx.x * blockDim.x + threadIdx.x;
    int node = gtid >> 6;
    int lane = threadIdx.x & 63;
    if (node >= N_NODES) return;
    int beg = row_ptr[node], end = row_ptr[node + 1];
    float acc = 0.f;
    int e = beg;
    for (; e + 1 < end; e += 2) {
        int2 p0 = sorted[e];
        int2 p1 = sorted[e + 1];
        float v0 = t2[p0.x * 64 + lane];
        float v1 = t2[p1.x * 64 + lane];
        acc = fmaf(__int_as_float(p0.y), v0, acc);
        acc = fmaf(__int_as_float(p1.y), v1, acc);
    }
    if (e < end) {
        int2 p = sorted[e];
        acc = fmaf(__int_as_float(p.y), t2[p.x * 64 + lane], acc);
    }
    float h = fmaxf(acc + b2[lane], 0.f) * W3[lane];
#pragma unroll
    for (int off = 32; off; off >>= 1) h += __shfl_down(h, off);
    if (lane == 0) t3[node] = h;
}

// ====== Layer 3: gather scalar t3 ======
__global__ void gather3(const int* __restrict__ row_ptr, const int2* __restrict__ sorted,
                        const float* __restrict__ t3, const float* __restrict__ b3,
                        float* __restrict__ out) {
    int i = blockIdx.x * blockDim.x + threadIdx.x;
    if (i >= N_NODES) return;
    int beg = row_ptr[i], end = row_ptr[i + 1];
    float acc = 0.f;
    for (int e = beg; e < end; e++) {
        int2 p = sorted[e];
        acc = fmaf(__int_as_float(p.y), t3[p.x], acc);
    }
    out[i] = acc + b3[0];
}

extern "C" void kernel_launch(void* const* d_in, const int* in_sizes, int n_in,
                              void* d_out, int out_size, void* d_ws, size_t ws_size,
                              hipStream_t stream) {
    const float* x  = (const float*)d_in[0];
    const int*   ei = (const int*)d_in[1];     // [2, E]
    const float* ew = (const float*)d_in[2];
    const float* W1 = (const float*)d_in[3];
    const float* b1 = (const float*)d_in[4];
    const float* W2 = (const float*)d_in[5];
    const float* b2 = (const float*)d_in[6];
    const float* W3 = (const float*)d_in[7];
    const float* b3 = (const float*)d_in[8];
    float* out = (float*)d_out;

    const int* src = ei;
    const int* dst = ei + N_EDGES;

    // workspace layout
    char* p = (char*)d_ws;
    int*  hist    = (int*)p;            p += N_NODES * sizeof(int);
    int*  row_ptr = (int*)p;            p += (N_NODES + 1) * sizeof(int);
    int*  cursor  = (int*)p;            p += N_NODES * sizeof(int);
    int*  incl    = (int*)p;            p += N_NODES * sizeof(int);
    int*  bsum    = (int*)p;            p += SCAN_NB * sizeof(int);
    p = (char*)(((uintptr_t)p + 15) & ~(uintptr_t)15);
    int2* sorted  = (int2*)p;           p += N_EDGES * sizeof(int2);       // 6.4 MB
    float* t2     = (float*)p;          p += 64 * N_NODES * sizeof(float); // 12.8 MB
    float* t3     = (float*)p;          p += N_NODES * sizeof(float);

    hipMemsetAsync(hist, 0, N_NODES * sizeof(int), stream);

    // CSR build
    hist_kernel<<<(N_EDGES + 255) / 256, 256, 0, stream>>>(dst, hist);
    scan_block_kernel<<<SCAN_NB, SCAN_BLOCK, 0, stream>>>(hist, incl, bsum);
    scan_top_kernel<<<1, SCAN_BLOCK, 0, stream>>>(bsum);
    scan_finish_kernel<<<SCAN_NB, SCAN_BLOCK, 0, stream>>>(hist, incl, bsum, row_ptr, cursor);
    scatter_edges<<<(N_EDGES + 255) / 256, 256, 0, stream>>>(src, dst, ew, cursor, sorted);

    // Layer 1 (fused gather + dense 2->128 + relu + dense 128->64)
    fused_l1<<<(N_NODES + L1_NODES_PER_BLOCK - 1) / L1_NODES_PER_BLOCK, 256, 0, stream>>>(
        row_ptr, sorted, x, W1, b1, W2, t2);

    // Layer 2 gather + fused layer-3 projection
    gather2_dot3<<<(N_NODES * 64 + 255) / 256, 256, 0, stream>>>(row_ptr, sorted, t2, b2, W3, t3);

    // Layer 3
    gather3<<<(N_NODES + 255) / 256, 256, 0, stream>>>(row_ptr, sorted, t3, b3, out);
}

// Round 4
// 263.075 us; speedup vs baseline: 3.7499x; 1.0995x over previous
//
#include <hip/hip_runtime.h>

#define N_NODES 50000
#define N_EDGES 800000
#define SCAN_BLOCK 256
#define SCAN_NB ((N_NODES + SCAN_BLOCK - 1) / SCAN_BLOCK)  // 196

// ================= CSR build (counting sort by dst) =================
__global__ void hist_kernel(const int* __restrict__ dst, int* __restrict__ hist) {
    int e = blockIdx.x * blockDim.x + threadIdx.x;
    if (e < N_EDGES) atomicAdd(&hist[dst[e]], 1);
}

__global__ void scan_block_kernel(const int* __restrict__ hist, int* __restrict__ incl,
                                  int* __restrict__ bsum) {
    __shared__ int lds[SCAN_BLOCK];
    int t = threadIdx.x;
    int i = blockIdx.x * SCAN_BLOCK + t;
    int v = (i < N_NODES) ? hist[i] : 0;
    lds[t] = v;
    __syncthreads();
    for (int off = 1; off < SCAN_BLOCK; off <<= 1) {
        int u = (t >= off) ? lds[t - off] : 0;
        __syncthreads();
        lds[t] += u;
        __syncthreads();
    }
    if (i < N_NODES) incl[i] = lds[t];
    if (t == SCAN_BLOCK - 1) bsum[blockIdx.x] = lds[t];
}

__global__ void scan_top_kernel(int* __restrict__ bsum) {
    __shared__ int lds[SCAN_BLOCK];
    int t = threadIdx.x;
    int v = (t < SCAN_NB) ? bsum[t] : 0;
    lds[t] = v;
    __syncthreads();
    for (int off = 1; off < SCAN_BLOCK; off <<= 1) {
        int u = (t >= off) ? lds[t - off] : 0;
        __syncthreads();
        lds[t] += u;
        __syncthreads();
    }
    if (t < SCAN_NB) bsum[t] = lds[t] - v;  // exclusive
}

__global__ void scan_finish_kernel(const int* __restrict__ hist, const int* __restrict__ incl,
                                   const int* __restrict__ bsum, int* __restrict__ row_ptr,
                                   int* __restrict__ cursor) {
    int i = blockIdx.x * SCAN_BLOCK + threadIdx.x;
    if (i == 0) row_ptr[N_NODES] = N_EDGES;
    if (i < N_NODES) {
        int ex = bsum[blockIdx.x] + incl[i] - hist[i];
        row_ptr[i] = ex;
        cursor[i] = ex;
    }
}

__global__ void scatter_edges(const int* __restrict__ src, const int* __restrict__ dst,
                              const float* __restrict__ ew, int* __restrict__ cursor,
                              int2* __restrict__ sorted) {
    int e = blockIdx.x * blockDim.x + threadIdx.x;
    if (e >= N_EDGES) return;
    int d = dst[e];
    int pos = atomicAdd(&cursor[d], 1);
    sorted[pos] = make_int2(src[e], __float_as_int(ew[e]));
}

// ====== Fused layer 1 (v2): wave-autonomous, 4 nodes per wave iteration ======
// gather x -> (a0,a1) with 16 lanes/node -> h1 = relu(.@W1+b1) (W1/b1 in regs)
// -> t2 = h1 @ W2 with w2s reads amortized over 4 nodes. No block barriers in loop.
#define L1_NPW 2                                 // node-groups of 4 per wave
#define L1_NODES_PER_BLOCK (4 * 4 * L1_NPW)      // 4 waves * 4 nodes * NPW = 32
__global__ void fused_l1(const int* __restrict__ row_ptr, const int2* __restrict__ sorted,
                         const float* __restrict__ x, const float* __restrict__ W1,
                         const float* __restrict__ b1, const float* __restrict__ W2,
                         float* __restrict__ t2) {
    __shared__ float w2s[128 * 64];      // 32 KB
    __shared__ float hls[4][4][128];     // [wave][node][feat], 8 KB  -> 40 KB total
    for (int k = threadIdx.x; k < 128 * 64; k += 256) w2s[k] = W2[k];
    int wave = threadIdx.x >> 6;
    int lane = threadIdx.x & 63;
    // per-lane W1/b1 slice in registers (lane = feature, +64 = second feature)
    float w1a = W1[lane],      w1b = W1[128 + lane];
    float w1c = W1[64 + lane], w1d = W1[192 + lane];
    float b1lo = b1[lane], b1hi = b1[64 + lane];
    __syncthreads();  // only barrier: w2s staged

    int sub = lane >> 4;       // which of 4 nodes this lane gathers for
    int sl  = lane & 15;

    for (int it = 0; it < L1_NPW; it++) {
        int base = blockIdx.x * L1_NODES_PER_BLOCK + wave * (4 * L1_NPW) + it * 4;
        // ---- gather phase: 16 lanes per node ----
        int gnode = base + sub;
        float a0 = 0.f, a1 = 0.f;
        if (gnode < N_NODES) {
            int beg = row_ptr[gnode], end = row_ptr[gnode + 1];
            for (int e = beg + sl; e < end; e += 16) {
                int2 p = sorted[e];
                float w = __int_as_float(p.y);
                float2 xv = ((const float2*)x)[p.x];
                a0 = fmaf(w, xv.x, a0);
                a1 = fmaf(w, xv.y, a1);
            }
        }
#pragma unroll
        for (int off = 1; off < 16; off <<= 1) {
            a0 += __shfl_xor(a0, off);
            a1 += __shfl_xor(a1, off);
        }
        // ---- h1 phase: each lane computes feats (lane, lane+64) for all 4 nodes ----
#pragma unroll
        for (int n = 0; n < 4; n++) {
            float an0 = __shfl(a0, 16 * n);
            float an1 = __shfl(a1, 16 * n);
            float hlo = fmaxf(fmaf(an0, w1a, fmaf(an1, w1b, b1lo)), 0.f);
            float hhi = fmaxf(fmaf(an0, w1c, fmaf(an1, w1d, b1hi)), 0.f);
            hls[wave][n][lane] = hlo;
            hls[wave][n][64 + lane] = hhi;
        }
        // same-wave LDS ops are program-ordered: no barrier needed
        // ---- dense phase: t2 row, w2s reads shared across 4 accumulators ----
        float acc0 = 0.f, acc1 = 0.f, acc2 = 0.f, acc3 = 0.f;
#pragma unroll 4
        for (int k4 = 0; k4 < 32; k4++) {
            float w0 = w2s[(4 * k4 + 0) * 64 + lane];
            float w1 = w2s[(4 * k4 + 1) * 64 + lane];
            float w2 = w2s[(4 * k4 + 2) * 64 + lane];
            float w3 = w2s[(4 * k4 + 3) * 64 + lane];
            float4 h0 = *(const float4*)&hls[wave][0][4 * k4];
            float4 h1 = *(const float4*)&hls[wave][1][4 * k4];
            float4 h2 = *(const float4*)&hls[wave][2][4 * k4];
            float4 h3 = *(const float4*)&hls[wave][3][4 * k4];
            acc0 = fmaf(h0.x, w0, fmaf(h0.y, w1, fmaf(h0.z, w2, fmaf(h0.w, w3, acc0))));
            acc1 = fmaf(h1.x, w0, fmaf(h1.y, w1, fmaf(h1.z, w2, fmaf(h1.w, w3, acc1))));
            acc2 = fmaf(h2.x, w0, fmaf(h2.y, w1, fmaf(h2.z, w2, fmaf(h2.w, w3, acc2))));
            acc3 = fmaf(h3.x, w0, fmaf(h3.y, w1, fmaf(h3.z, w2, fmaf(h3.w, w3, acc3))));
        }
        if (base + 0 < N_NODES) t2[(base + 0) * 64 + lane] = acc0;
        if (base + 1 < N_NODES) t2[(base + 1) * 64 + lane] = acc1;
        if (base + 2 < N_NODES) t2[(base + 2) * 64 + lane] = acc2;
        if (base + 3 < N_NODES) t2[(base + 3) * 64 + lane] = acc3;
    }
}

// ====== Layer 2 gather + fused layer-3 projection (wave per node) ======
__global__ void gather2_dot3(const int* __restrict__ row_ptr, const int2* __restrict__ sorted,
                             const float* __restrict__ t2, const float* __restrict__ b2,
                             const float* __restrict__ W3, float* __restrict__ t3) {
    int gtid = blockIdx.x * blockDim.x + threadIdx.x;
    int node = gtid >> 6;
    int lane = threadIdx.x & 63;
    if (node >= N_NODES) return;
    int beg = row_ptr[node], end = row_ptr[node + 1];
    float acc = 0.f;
    int e = beg;
    for (; e + 1 < end; e += 2) {
        int2 p0 = sorted[e];
        int2 p1 = sorted[e + 1];
        float v0 = t2[p0.x * 64 + lane];
        float v1 = t2[p1.x * 64 + lane];
        acc = fmaf(__int_as_float(p0.y), v0, acc);
        acc = fmaf(__int_as_float(p1.y), v1, acc);
    }
    if (e < end) {
        int2 p = sorted[e];
        acc = fmaf(__int_as_float(p.y), t2[p.x * 64 + lane], acc);
    }
    float h = fmaxf(acc + b2[lane], 0.f) * W3[lane];
#pragma unroll
    for (int off = 32; off; off >>= 1) h += __shfl_down(h, off);
    if (lane == 0) t3[node] = h;
}

// ====== Layer 3: gather scalar t3 ======
__global__ void gather3(const int* __restrict__ row_ptr, const int2* __restrict__ sorted,
                        const float* __restrict__ t3, const float* __restrict__ b3,
                        float* __restrict__ out) {
    int i = blockIdx.x * blockDim.x + threadIdx.x;
    if (i >= N_NODES) return;
    int beg = row_ptr[i], end = row_ptr[i + 1];
    float acc = 0.f;
    for (int e = beg; e < end; e++) {
        int2 p = sorted[e];
        acc = fmaf(__int_as_float(p.y), t3[p.x], acc);
    }
    out[i] = acc + b3[0];
}

extern "C" void kernel_launch(void* const* d_in, const int* in_sizes, int n_in,
                              void* d_out, int out_size, void* d_ws, size_t ws_size,
                              hipStream_t stream) {
    const float* x  = (const float*)d_in[0];
    const int*   ei = (const int*)d_in[1];     // [2, E]
    const float* ew = (const float*)d_in[2];
    const float* W1 = (const float*)d_in[3];
    const float* b1 = (const float*)d_in[4];
    const float* W2 = (const float*)d_in[5];
    const float* b2 = (const float*)d_in[6];
    const float* W3 = (const float*)d_in[7];
    const float* b3 = (const float*)d_in[8];
    float* out = (float*)d_out;

    const int* src = ei;
    const int* dst = ei + N_EDGES;

    // workspace layout
    char* p = (char*)d_ws;
    int*  hist    = (int*)p;            p += N_NODES * sizeof(int);
    int*  row_ptr = (int*)p;            p += (N_NODES + 1) * sizeof(int);
    int*  cursor  = (int*)p;            p += N_NODES * sizeof(int);
    int*  incl    = (int*)p;            p += N_NODES * sizeof(int);
    int*  bsum    = (int*)p;            p += SCAN_NB * sizeof(int);
    p = (char*)(((uintptr_t)p + 15) & ~(uintptr_t)15);
    int2* sorted  = (int2*)p;           p += N_EDGES * sizeof(int2);       // 6.4 MB
    float* t2     = (float*)p;          p += 64 * N_NODES * sizeof(float); // 12.8 MB
    float* t3     = (float*)p;          p += N_NODES * sizeof(float);

    hipMemsetAsync(hist, 0, N_NODES * sizeof(int), stream);

    // CSR build
    hist_kernel<<<(N_EDGES + 255) / 256, 256, 0, stream>>>(dst, hist);
    scan_block_kernel<<<SCAN_NB, SCAN_BLOCK, 0, stream>>>(hist, incl, bsum);
    scan_top_kernel<<<1, SCAN_BLOCK, 0, stream>>>(bsum);
    scan_finish_kernel<<<SCAN_NB, SCAN_BLOCK, 0, stream>>>(hist, incl, bsum, row_ptr, cursor);
    scatter_edges<<<(N_EDGES + 255) / 256, 256, 0, stream>>>(src, dst, ew, cursor, sorted);

    // Layer 1 (fused gather + dense 2->128 + relu + dense 128->64)
    fused_l1<<<(N_NODES + L1_NODES_PER_BLOCK - 1) / L1_NODES_PER_BLOCK, 256, 0, stream>>>(
        row_ptr, sorted, x, W1, b1, W2, t2);

    // Layer 2 gather + fused layer-3 projection
    gather2_dot3<<<(N_NODES * 64 + 255) / 256, 256, 0, stream>>>(row_ptr, sorted, t2, b2, W3, t3);

    // Layer 3
    gather3<<<(N_NODES + 255) / 256, 256, 0, stream>>>(row_ptr, sorted, t3, b3, out);
}

// Round 5
// 208.256 us; speedup vs baseline: 4.7370x; 1.2632x over previous
//
#include <hip/hip_runtime.h>
#include <hip/hip_fp16.h>

#define N_NODES 50000
#define N_EDGES 800000
#define BSHIFT 8
#define NBKT ((N_NODES + 255) >> BSHIFT)              // 196 buckets of 256 nodes
#define P1_EDGES 8192
#define P1_BLOCKS ((N_EDGES + P1_EDGES - 1) / P1_EDGES)  // 98

// ===== Pass 0: coarse histogram over NBKT buckets =====
__global__ void coarse_hist(const int* __restrict__ dst, int* __restrict__ gtot) {
    __shared__ int h[256];
    h[threadIdx.x] = 0;
    __syncthreads();
    for (int e = blockIdx.x * blockDim.x + threadIdx.x; e < N_EDGES; e += gridDim.x * blockDim.x)
        atomicAdd(&h[dst[e] >> BSHIFT], 1);
    __syncthreads();
    int t = threadIdx.x;
    if (t < NBKT && h[t]) atomicAdd(&gtot[t], h[t]);
}

// ===== scan bucket totals -> bucket base + cursor (1 block) =====
__global__ void scan_buckets(const int* __restrict__ gtot, int* __restrict__ bbase,
                             int* __restrict__ bcur) {
    __shared__ int lds[256];
    int t = threadIdx.x;
    int v = (t < NBKT) ? gtot[t] : 0;
    lds[t] = v;
    __syncthreads();
    for (int off = 1; off < 256; off <<= 1) {
        int u = (t >= off) ? lds[t - off] : 0;
        __syncthreads();
        lds[t] += u;
        __syncthreads();
    }
    if (t < NBKT) { int ex = lds[t] - v; bbase[t] = ex; bcur[t] = ex; }
    if (t == 0) bbase[NBKT] = N_EDGES;
}

// ===== Pass 1: bin edges into bucket regions (chunk-reserved, write-combining) =====
// binned payload: {src | (dst&255)<<16, bits(w)}
__global__ void bin_edges(const int* __restrict__ src, const int* __restrict__ dst,
                          const float* __restrict__ ew, int* __restrict__ bcur,
                          int2* __restrict__ binned) {
    __shared__ int cnt[256];
    __shared__ int cbase[256];
    __shared__ int lcur[256];
    int t = threadIdx.x;
    cnt[t] = 0;
    __syncthreads();
    int e0 = blockIdx.x * P1_EDGES;
    for (int k = 0; k < P1_EDGES / 256; k++) {
        int e = e0 + k * 256 + t;
        if (e < N_EDGES) atomicAdd(&cnt[dst[e] >> BSHIFT], 1);
    }
    __syncthreads();
    if (t < NBKT) {
        int v = cnt[t];
        cbase[t] = v ? atomicAdd(&bcur[t], v) : 0;
        lcur[t] = 0;
    }
    __syncthreads();
    for (int k = 0; k < P1_EDGES / 256; k++) {
        int e = e0 + k * 256 + t;
        if (e < N_EDGES) {
            int d = dst[e];
            int b = d >> BSHIFT;
            int pos = cbase[b] + atomicAdd(&lcur[b], 1);
            binned[pos] = make_int2(src[e] | ((d & 255) << 16), __float_as_int(ew[e]));
        }
    }
}

// ===== Pass 2: sort each bucket by exact dst (L2-resident region), emit row_ptr =====
__global__ void sort_bucket(const int* __restrict__ bbase, const int2* __restrict__ binned,
                            int2* __restrict__ sorted, int* __restrict__ row_ptr) {
    __shared__ int nh[256];
    __shared__ int scn[256];
    __shared__ int lcur[256];
    int b = blockIdx.x;
    int t = threadIdx.x;
    int beg = bbase[b], end = bbase[b + 1];
    nh[t] = 0;
    __syncthreads();
    for (int e = beg + t; e < end; e += 256)
        atomicAdd(&nh[(binned[e].x >> 16) & 255], 1);
    __syncthreads();
    int v = nh[t];
    scn[t] = v;
    __syncthreads();
    for (int off = 1; off < 256; off <<= 1) {
        int u = (t >= off) ? scn[t - off] : 0;
        __syncthreads();
        scn[t] += u;
        __syncthreads();
    }
    int ex = scn[t] - v;  // exclusive offset for dlow = t
    int node = (b << BSHIFT) + t;
    if (node < N_NODES) row_ptr[node] = beg + ex;
    __syncthreads();
    nh[t] = ex;      // repurpose as exclusive-offset table
    lcur[t] = 0;
    __syncthreads();
    for (int e = beg + t; e < end; e += 256) {
        int2 p = binned[e];
        int dlow = (p.x >> 16) & 255;
        int pos = beg + nh[dlow] + atomicAdd(&lcur[dlow], 1);
        sorted[pos] = make_int2(p.x & 0xFFFF, p.y);
    }
    if (b == 0 && t == 0) row_ptr[N_NODES] = N_EDGES;
}

// ====== Fused layer 1: gather x -> h1 = relu(.@W1+b1) -> t2 = h1 @ W2 (fp16 out) ======
#define L1_NPW 2
#define L1_NODES_PER_BLOCK (4 * 4 * L1_NPW)  // 32
__global__ void fused_l1(const int* __restrict__ row_ptr, const int2* __restrict__ sorted,
                         const float* __restrict__ x, const float* __restrict__ W1,
                         const float* __restrict__ b1, const float* __restrict__ W2,
                         __half* __restrict__ t2) {
    __shared__ float w2s[128 * 64];
    __shared__ float hls[4][4][128];
    for (int k = threadIdx.x; k < 128 * 64; k += 256) w2s[k] = W2[k];
    int wave = threadIdx.x >> 6;
    int lane = threadIdx.x & 63;
    float w1a = W1[lane],      w1b = W1[128 + lane];
    float w1c = W1[64 + lane], w1d = W1[192 + lane];
    float b1lo = b1[lane], b1hi = b1[64 + lane];
    __syncthreads();

    int sub = lane >> 4;
    int sl  = lane & 15;

    for (int it = 0; it < L1_NPW; it++) {
        int base = blockIdx.x * L1_NODES_PER_BLOCK + wave * (4 * L1_NPW) + it * 4;
        int gnode = base + sub;
        float a0 = 0.f, a1 = 0.f;
        if (gnode < N_NODES) {
            int beg = row_ptr[gnode], end = row_ptr[gnode + 1];
            for (int e = beg + sl; e < end; e += 16) {
                int2 p = sorted[e];
                float w = __int_as_float(p.y);
                float2 xv = ((const float2*)x)[p.x];
                a0 = fmaf(w, xv.x, a0);
                a1 = fmaf(w, xv.y, a1);
            }
        }
#pragma unroll
        for (int off = 1; off < 16; off <<= 1) {
            a0 += __shfl_xor(a0, off);
            a1 += __shfl_xor(a1, off);
        }
#pragma unroll
        for (int n = 0; n < 4; n++) {
            float an0 = __shfl(a0, 16 * n);
            float an1 = __shfl(a1, 16 * n);
            float hlo = fmaxf(fmaf(an0, w1a, fmaf(an1, w1b, b1lo)), 0.f);
            float hhi = fmaxf(fmaf(an0, w1c, fmaf(an1, w1d, b1hi)), 0.f);
            hls[wave][n][lane] = hlo;
            hls[wave][n][64 + lane] = hhi;
        }
        float acc0 = 0.f, acc1 = 0.f, acc2 = 0.f, acc3 = 0.f;
#pragma unroll 4
        for (int k4 = 0; k4 < 32; k4++) {
            float w0 = w2s[(4 * k4 + 0) * 64 + lane];
            float w1 = w2s[(4 * k4 + 1) * 64 + lane];
            float w2 = w2s[(4 * k4 + 2) * 64 + lane];
            float w3 = w2s[(4 * k4 + 3) * 64 + lane];
            float4 h0 = *(const float4*)&hls[wave][0][4 * k4];
            float4 h1 = *(const float4*)&hls[wave][1][4 * k4];
            float4 h2 = *(const float4*)&hls[wave][2][4 * k4];
            float4 h3 = *(const float4*)&hls[wave][3][4 * k4];
            acc0 = fmaf(h0.x, w0, fmaf(h0.y, w1, fmaf(h0.z, w2, fmaf(h0.w, w3, acc0))));
            acc1 = fmaf(h1.x, w0, fmaf(h1.y, w1, fmaf(h1.z, w2, fmaf(h1.w, w3, acc1))));
            acc2 = fmaf(h2.x, w0, fmaf(h2.y, w1, fmaf(h2.z, w2, fmaf(h2.w, w3, acc2))));
            acc3 = fmaf(h3.x, w0, fmaf(h3.y, w1, fmaf(h3.z, w2, fmaf(h3.w, w3, acc3))));
        }
        if (base + 0 < N_NODES) t2[(base + 0) * 64 + lane] = __float2half(acc0);
        if (base + 1 < N_NODES) t2[(base + 1) * 64 + lane] = __float2half(acc1);
        if (base + 2 < N_NODES) t2[(base + 2) * 64 + lane] = __float2half(acc2);
        if (base + 3 < N_NODES) t2[(base + 3) * 64 + lane] = __float2half(acc3);
    }
}

// ====== Layer 2 gather (fp16 rows) + fused layer-3 projection ======
__global__ void gather2_dot3(const int* __restrict__ row_ptr, const int2* __restrict__ sorted,
                             const __half* __restrict__ t2, const float* __restrict__ b2,
                             const float* __restrict__ W3, float* __restrict__ t3) {
    int gtid = blockIdx.x * blockDim.x + threadIdx.x;
    int node = gtid >> 6;
    int lane = threadIdx.x & 63;
    if (node >= N_NODES) return;
    int beg = row_ptr[node], end = row_ptr[node + 1];
    float accA = 0.f, accB = 0.f;
    int e = beg;
    for (; e + 3 < end; e += 4) {
        int2 p0 = sorted[e];
        int2 p1 = sorted[e + 1];
        int2 p2 = sorted[e + 2];
        int2 p3 = sorted[e + 3];
        float v0 = __half2float(t2[p0.x * 64 + lane]);
        float v1 = __half2float(t2[p1.x * 64 + lane]);
        float v2 = __half2float(t2[p2.x * 64 + lane]);
        float v3 = __half2float(t2[p3.x * 64 + lane]);
        accA = fmaf(__int_as_float(p0.y), v0, accA);
        accB = fmaf(__int_as_float(p1.y), v1, accB);
        accA = fmaf(__int_as_float(p2.y), v2, accA);
        accB = fmaf(__int_as_float(p3.y), v3, accB);
    }
    for (; e < end; e++) {
        int2 p = sorted[e];
        accA = fmaf(__int_as_float(p.y), __half2float(t2[p.x * 64 + lane]), accA);
    }
    float h = fmaxf(accA + accB + b2[lane], 0.f) * W3[lane];
#pragma unroll
    for (int off = 32; off; off >>= 1) h += __shfl_down(h, off);
    if (lane == 0) t3[node] = h;
}

// ====== Layer 3: gather scalar t3 ======
__global__ void gather3(const int* __restrict__ row_ptr, const int2* __restrict__ sorted,
                        const float* __restrict__ t3, const float* __restrict__ b3,
                        float* __restrict__ out) {
    int i = blockIdx.x * blockDim.x + threadIdx.x;
    if (i >= N_NODES) return;
    int beg = row_ptr[i], end = row_ptr[i + 1];
    float acc = 0.f;
    for (int e = beg; e < end; e++) {
        int2 p = sorted[e];
        acc = fmaf(__int_as_float(p.y), t3[p.x], acc);
    }
    out[i] = acc + b3[0];
}

extern "C" void kernel_launch(void* const* d_in, const int* in_sizes, int n_in,
                              void* d_out, int out_size, void* d_ws, size_t ws_size,
                              hipStream_t stream) {
    const float* x  = (const float*)d_in[0];
    const int*   ei = (const int*)d_in[1];     // [2, E]
    const float* ew = (const float*)d_in[2];
    const float* W1 = (const float*)d_in[3];
    const float* b1 = (const float*)d_in[4];
    const float* W2 = (const float*)d_in[5];
    const float* b2 = (const float*)d_in[6];
    const float* W3 = (const float*)d_in[7];
    const float* b3 = (const float*)d_in[8];
    float* out = (float*)d_out;

    const int* src = ei;
    const int* dst = ei + N_EDGES;

    // workspace layout
    char* p = (char*)d_ws;
    int*  gtot    = (int*)p;            p += NBKT * sizeof(int);
    int*  bbase   = (int*)p;            p += (NBKT + 1) * sizeof(int);
    int*  bcur    = (int*)p;            p += NBKT * sizeof(int);
    int*  row_ptr = (int*)p;            p += (N_NODES + 1) * sizeof(int);
    p = (char*)(((uintptr_t)p + 15) & ~(uintptr_t)15);
    int2* binned  = (int2*)p;           p += N_EDGES * sizeof(int2);       // 6.4 MB
    int2* sorted  = (int2*)p;           p += N_EDGES * sizeof(int2);       // 6.4 MB
    __half* t2    = (__half*)p;         p += 64 * N_NODES * sizeof(__half);// 6.4 MB
    float* t3     = (float*)p;          p += N_NODES * sizeof(float);

    hipMemsetAsync(gtot, 0, NBKT * sizeof(int), stream);

    // CSR build: coarse hist -> scan -> bin -> per-bucket sort
    coarse_hist<<<256, 256, 0, stream>>>(dst, gtot);
    scan_buckets<<<1, 256, 0, stream>>>(gtot, bbase, bcur);
    bin_edges<<<P1_BLOCKS, 256, 0, stream>>>(src, dst, ew, bcur, binned);
    sort_bucket<<<NBKT, 256, 0, stream>>>(bbase, binned, sorted, row_ptr);

    // Layer 1 (fused gather + dense 2->128 + relu + dense 128->64, fp16 out)
    fused_l1<<<(N_NODES + L1_NODES_PER_BLOCK - 1) / L1_NODES_PER_BLOCK, 256, 0, stream>>>(
        row_ptr, sorted, x, W1, b1, W2, t2);

    // Layer 2 gather + fused layer-3 projection
    gather2_dot3<<<(N_NODES * 64 + 255) / 256, 256, 0, stream>>>(row_ptr, sorted, t2, b2, W3, t3);

    // Layer 3
    gather3<<<(N_NODES + 255) / 256, 256, 0, stream>>>(row_ptr, sorted, t3, b3, out);
}

// Round 6
// 201.324 us; speedup vs baseline: 4.9001x; 1.0344x over previous
//
#include <hip/hip_runtime.h>
#include <hip/hip_fp16.h>

#define N_NODES 50000
#define N_EDGES 800000
#define BSHIFT 8
#define NBKT ((N_NODES + 255) >> BSHIFT)                 // 196 buckets of 256 nodes
#define P1_EDGES 4096
#define P1_BLOCKS ((N_EDGES + P1_EDGES - 1) / P1_EDGES)  // 196

// ===== Pass 0: per-block bucket counts -> cnt[blk][bucket] =====
__global__ void count_kernel(const int* __restrict__ dst, int* __restrict__ cnt) {
    __shared__ int h[NBKT];
    int t = threadIdx.x;
    if (t < NBKT) h[t] = 0;
    __syncthreads();
    int e0 = blockIdx.x * P1_EDGES;
    for (int k = 0; k < P1_EDGES / 256; k++) {
        int e = e0 + k * 256 + t;
        if (e < N_EDGES) atomicAdd(&h[dst[e] >> BSHIFT], 1);
    }
    __syncthreads();
    if (t < NBKT) cnt[blockIdx.x * NBKT + t] = h[t];
}

// ===== Pass 0.5: turn cnt into exact per-(block,bucket) cursors; emit bucket bases =====
__global__ void scan_matrix(int* __restrict__ cnt, int* __restrict__ bbase) {
    __shared__ int lds[256];
    int t = threadIdx.x;
    int tot = 0;
    if (t < NBKT) {
        for (int blk = 0; blk < P1_BLOCKS; blk++) {
            int idx = blk * NBKT + t;
            int v = cnt[idx];
            cnt[idx] = tot;        // exclusive-within-bucket prefix over blocks
            tot += v;
        }
    }
    lds[t] = (t < NBKT) ? tot : 0;
    __syncthreads();
    for (int off = 1; off < 256; off <<= 1) {
        int u = (t >= off) ? lds[t - off] : 0;
        __syncthreads();
        lds[t] += u;
        __syncthreads();
    }
    int ex = lds[t] - ((t < NBKT) ? tot : 0);
    if (t < NBKT) {
        bbase[t] = ex;
        for (int blk = 0; blk < P1_BLOCKS; blk++) cnt[blk * NBKT + t] += ex;
    }
    if (t == 0) bbase[NBKT] = N_EDGES;
}

// ===== Pass 1: bin edges into bucket regions (LDS cursors only, no global atomics) =====
// binned payload: {src | (dst&255)<<16, bits(w)}
__global__ void bin_edges(const int* __restrict__ src, const int* __restrict__ dst,
                          const float* __restrict__ ew, const int* __restrict__ cnt,
                          int2* __restrict__ binned) {
    __shared__ int lcur[NBKT];
    int t = threadIdx.x;
    if (t < NBKT) lcur[t] = cnt[blockIdx.x * NBKT + t];
    __syncthreads();
    int e0 = blockIdx.x * P1_EDGES;
    for (int k = 0; k < P1_EDGES / 256; k++) {
        int e = e0 + k * 256 + t;
        if (e < N_EDGES) {
            int d = dst[e];
            int b = d >> BSHIFT;
            int pos = atomicAdd(&lcur[b], 1);
            binned[pos] = make_int2(src[e] | ((d & 255) << 16), __float_as_int(ew[e]));
        }
    }
}

// ===== Pass 2: sort each bucket by exact dst, emit row_ptr + packed 4B edges =====
// packed edge: src(16) | fp16 weight(16)
__global__ void sort_bucket(const int* __restrict__ bbase, const int2* __restrict__ binned,
                            unsigned* __restrict__ sorted, int* __restrict__ row_ptr) {
    __shared__ int nh[256];
    __shared__ int scn[256];
    __shared__ int lcur[256];
    int b = blockIdx.x;
    int t = threadIdx.x;
    int beg = bbase[b], end = bbase[b + 1];
    nh[t] = 0;
    __syncthreads();
    for (int e = beg + t; e < end; e += 256)
        atomicAdd(&nh[(binned[e].x >> 16) & 255], 1);
    __syncthreads();
    int v = nh[t];
    scn[t] = v;
    __syncthreads();
    for (int off = 1; off < 256; off <<= 1) {
        int u = (t >= off) ? scn[t - off] : 0;
        __syncthreads();
        scn[t] += u;
        __syncthreads();
    }
    int ex = scn[t] - v;
    int node = (b << BSHIFT) + t;
    if (node < N_NODES) row_ptr[node] = beg + ex;
    __syncthreads();
    nh[t] = ex;
    lcur[t] = 0;
    __syncthreads();
    for (int e = beg + t; e < end; e += 256) {
        int2 p = binned[e];
        int dlow = (p.x >> 16) & 255;
        int pos = beg + nh[dlow] + atomicAdd(&lcur[dlow], 1);
        unsigned hw = (unsigned)__half_as_ushort(__float2half(__int_as_float(p.y)));
        sorted[pos] = (unsigned)(p.x & 0xFFFF) | (hw << 16);
    }
    if (b == 0 && t == 0) row_ptr[N_NODES] = N_EDGES;
}

__device__ __forceinline__ float edge_w(unsigned p) {
    return __half2float(__ushort_as_half((unsigned short)(p >> 16)));
}

// ====== Fused layer 1: gather x -> h1 = relu(.@W1+b1) -> t2 = h1 @ W2 (fp16 out) ======
#define L1_NPW 2
#define L1_NODES_PER_BLOCK (4 * 4 * L1_NPW)  // 32
__global__ void fused_l1(const int* __restrict__ row_ptr, const unsigned* __restrict__ sorted,
                         const float* __restrict__ x, const float* __restrict__ W1,
                         const float* __restrict__ b1, const float* __restrict__ W2,
                         __half* __restrict__ t2) {
    __shared__ float w2s[128 * 64];
    __shared__ float hls[4][4][128];
    for (int k = threadIdx.x; k < 128 * 64; k += 256) w2s[k] = W2[k];
    int wave = threadIdx.x >> 6;
    int lane = threadIdx.x & 63;
    float w1a = W1[lane],      w1b = W1[128 + lane];
    float w1c = W1[64 + lane], w1d = W1[192 + lane];
    float b1lo = b1[lane], b1hi = b1[64 + lane];
    __syncthreads();

    int sub = lane >> 4;
    int sl  = lane & 15;

    for (int it = 0; it < L1_NPW; it++) {
        int base = blockIdx.x * L1_NODES_PER_BLOCK + wave * (4 * L1_NPW) + it * 4;
        int gnode = base + sub;
        float a0 = 0.f, a1 = 0.f;
        if (gnode < N_NODES) {
            int beg = row_ptr[gnode], end = row_ptr[gnode + 1];
            for (int e = beg + sl; e < end; e += 16) {
                unsigned p = sorted[e];
                float w = edge_w(p);
                float2 xv = ((const float2*)x)[p & 0xFFFF];
                a0 = fmaf(w, xv.x, a0);
                a1 = fmaf(w, xv.y, a1);
            }
        }
#pragma unroll
        for (int off = 1; off < 16; off <<= 1) {
            a0 += __shfl_xor(a0, off);
            a1 += __shfl_xor(a1, off);
        }
#pragma unroll
        for (int n = 0; n < 4; n++) {
            float an0 = __shfl(a0, 16 * n);
            float an1 = __shfl(a1, 16 * n);
            float hlo = fmaxf(fmaf(an0, w1a, fmaf(an1, w1b, b1lo)), 0.f);
            float hhi = fmaxf(fmaf(an0, w1c, fmaf(an1, w1d, b1hi)), 0.f);
            hls[wave][n][lane] = hlo;
            hls[wave][n][64 + lane] = hhi;
        }
        float acc0 = 0.f, acc1 = 0.f, acc2 = 0.f, acc3 = 0.f;
#pragma unroll 4
        for (int k4 = 0; k4 < 32; k4++) {
            float w0 = w2s[(4 * k4 + 0) * 64 + lane];
            float w1 = w2s[(4 * k4 + 1) * 64 + lane];
            float w2 = w2s[(4 * k4 + 2) * 64 + lane];
            float w3 = w2s[(4 * k4 + 3) * 64 + lane];
            float4 h0 = *(const float4*)&hls[wave][0][4 * k4];
            float4 h1 = *(const float4*)&hls[wave][1][4 * k4];
            float4 h2 = *(const float4*)&hls[wave][2][4 * k4];
            float4 h3 = *(const float4*)&hls[wave][3][4 * k4];
            acc0 = fmaf(h0.x, w0, fmaf(h0.y, w1, fmaf(h0.z, w2, fmaf(h0.w, w3, acc0))));
            acc1 = fmaf(h1.x, w0, fmaf(h1.y, w1, fmaf(h1.z, w2, fmaf(h1.w, w3, acc1))));
            acc2 = fmaf(h2.x, w0, fmaf(h2.y, w1, fmaf(h2.z, w2, fmaf(h2.w, w3, acc2))));
            acc3 = fmaf(h3.x, w0, fmaf(h3.y, w1, fmaf(h3.z, w2, fmaf(h3.w, w3, acc3))));
        }
        if (base + 0 < N_NODES) t2[(base + 0) * 64 + lane] = __float2half(acc0);
        if (base + 1 < N_NODES) t2[(base + 1) * 64 + lane] = __float2half(acc1);
        if (base + 2 < N_NODES) t2[(base + 2) * 64 + lane] = __float2half(acc2);
        if (base + 3 < N_NODES) t2[(base + 3) * 64 + lane] = __float2half(acc3);
    }
}

// ====== Layer 2 gather (fp16 rows) + fused layer-3 projection ======
__global__ void gather2_dot3(const int* __restrict__ row_ptr, const unsigned* __restrict__ sorted,
                             const __half* __restrict__ t2, const float* __restrict__ b2,
                             const float* __restrict__ W3, float* __restrict__ t3) {
    int gtid = blockIdx.x * blockDim.x + threadIdx.x;
    int node = gtid >> 6;
    int lane = threadIdx.x & 63;
    if (node >= N_NODES) return;
    int beg = row_ptr[node], end = row_ptr[node + 1];
    float accA = 0.f, accB = 0.f;
    int e = beg;
    for (; e + 3 < end; e += 4) {
        unsigned p0 = sorted[e];
        unsigned p1 = sorted[e + 1];
        unsigned p2 = sorted[e + 2];
        unsigned p3 = sorted[e + 3];
        float v0 = __half2float(t2[(p0 & 0xFFFF) * 64 + lane]);
        float v1 = __half2float(t2[(p1 & 0xFFFF) * 64 + lane]);
        float v2 = __half2float(t2[(p2 & 0xFFFF) * 64 + lane]);
        float v3 = __half2float(t2[(p3 & 0xFFFF) * 64 + lane]);
        accA = fmaf(edge_w(p0), v0, accA);
        accB = fmaf(edge_w(p1), v1, accB);
        accA = fmaf(edge_w(p2), v2, accA);
        accB = fmaf(edge_w(p3), v3, accB);
    }
    for (; e < end; e++) {
        unsigned p = sorted[e];
        accA = fmaf(edge_w(p), __half2float(t2[(p & 0xFFFF) * 64 + lane]), accA);
    }
    float h = fmaxf(accA + accB + b2[lane], 0.f) * W3[lane];
#pragma unroll
    for (int off = 32; off; off >>= 1) h += __shfl_down(h, off);
    if (lane == 0) t3[node] = h;
}

// ====== Layer 3: gather scalar t3 ======
__global__ void gather3(const int* __restrict__ row_ptr, const unsigned* __restrict__ sorted,
                        const float* __restrict__ t3, const float* __restrict__ b3,
                        float* __restrict__ out) {
    int i = blockIdx.x * blockDim.x + threadIdx.x;
    if (i >= N_NODES) return;
    int beg = row_ptr[i], end = row_ptr[i + 1];
    float acc = 0.f;
    for (int e = beg; e < end; e++) {
        unsigned p = sorted[e];
        acc = fmaf(edge_w(p), t3[p & 0xFFFF], acc);
    }
    out[i] = acc + b3[0];
}

extern "C" void kernel_launch(void* const* d_in, const int* in_sizes, int n_in,
                              void* d_out, int out_size, void* d_ws, size_t ws_size,
                              hipStream_t stream) {
    const float* x  = (const float*)d_in[0];
    const int*   ei = (const int*)d_in[1];     // [2, E]
    const float* ew = (const float*)d_in[2];
    const float* W1 = (const float*)d_in[3];
    const float* b1 = (const float*)d_in[4];
    const float* W2 = (const float*)d_in[5];
    const float* b2 = (const float*)d_in[6];
    const float* W3 = (const float*)d_in[7];
    const float* b3 = (const float*)d_in[8];
    float* out = (float*)d_out;

    const int* src = ei;
    const int* dst = ei + N_EDGES;

    // workspace layout
    char* p = (char*)d_ws;
    int*  cnt     = (int*)p;            p += P1_BLOCKS * NBKT * sizeof(int);  // 153 KB
    int*  bbase   = (int*)p;            p += (NBKT + 1) * sizeof(int);
    int*  row_ptr = (int*)p;            p += (N_NODES + 1) * sizeof(int);
    p = (char*)(((uintptr_t)p + 15) & ~(uintptr_t)15);
    int2* binned      = (int2*)p;       p += N_EDGES * sizeof(int2);          // 6.4 MB
    unsigned* sorted  = (unsigned*)p;   p += N_EDGES * sizeof(unsigned);      // 3.2 MB
    __half* t2    = (__half*)p;         p += 64 * N_NODES * sizeof(__half);   // 6.4 MB
    float* t3     = (float*)p;          p += N_NODES * sizeof(float);

    // CSR build: count matrix -> cursor scan -> bin -> per-bucket sort
    count_kernel<<<P1_BLOCKS, 256, 0, stream>>>(dst, cnt);
    scan_matrix<<<1, 256, 0, stream>>>(cnt, bbase);
    bin_edges<<<P1_BLOCKS, 256, 0, stream>>>(src, dst, ew, cnt, binned);
    sort_bucket<<<NBKT, 256, 0, stream>>>(bbase, binned, sorted, row_ptr);

    // Layer 1 (fused gather + dense 2->128 + relu + dense 128->64, fp16 out)
    fused_l1<<<(N_NODES + L1_NODES_PER_BLOCK - 1) / L1_NODES_PER_BLOCK, 256, 0, stream>>>(
        row_ptr, sorted, x, W1, b1, W2, t2);

    // Layer 2 gather + fused layer-3 projection
    gather2_dot3<<<(N_NODES * 64 + 255) / 256, 256, 0, stream>>>(row_ptr, sorted, t2, b2, W3, t3);

    // Layer 3
    gather3<<<(N_NODES + 255) / 256, 256, 0, stream>>>(row_ptr, sorted, t3, b3, out);
}

// Round 7
// 196.817 us; speedup vs baseline: 5.0124x; 1.0229x over previous
//
#include <hip/hip_runtime.h>
#include <hip/hip_fp16.h>

#define N_NODES 50000
#define N_EDGES 800000
#define BSHIFT 8
#define NBKT ((N_NODES + 255) >> BSHIFT)                 // 196 buckets of 256 nodes
#define P1_EDGES 4096
#define P1_BLOCKS ((N_EDGES + P1_EDGES - 1) / P1_EDGES)  // 196
#define NSEG 4
#define SEG_LEN ((P1_BLOCKS + NSEG - 1) / NSEG)          // 49

// ===== Pass 0: per-block bucket counts -> cnt[blk][bucket] =====
__global__ void count_kernel(const int* __restrict__ dst, int* __restrict__ cnt) {
    __shared__ int h[NBKT];
    int t = threadIdx.x;
    if (t < NBKT) h[t] = 0;
    __syncthreads();
    int e0 = blockIdx.x * P1_EDGES;
    for (int k = 0; k < P1_EDGES / 256; k++) {
        int e = e0 + k * 256 + t;
        if (e < N_EDGES) atomicAdd(&h[dst[e] >> BSHIFT], 1);
    }
    __syncthreads();
    if (t < NBKT) cnt[blockIdx.x * NBKT + t] = h[t];
}

// ===== Pass 0.5: cnt -> exact per-(block,bucket) cursors; bucket bases. 4-way segmented. =====
__global__ void scan_matrix(int* __restrict__ cnt, int* __restrict__ bbase) {
    __shared__ int segsum[NSEG][256];
    __shared__ int btot[256];
    int t = threadIdx.x & 255;   // bucket
    int s = threadIdx.x >> 8;    // segment
    int sum = 0;
    if (t < NBKT) {
        for (int i = 0; i < SEG_LEN; i++) {
            int blk = s * SEG_LEN + i;
            if (blk < P1_BLOCKS) sum += cnt[blk * NBKT + t];
        }
    }
    segsum[s][t] = sum;
    __syncthreads();
    int tot = 0;
    if (s == 0) {
        int run = 0;
        for (int ss = 0; ss < NSEG; ss++) { int v = segsum[ss][t]; segsum[ss][t] = run; run += v; }
        tot = run;
        btot[t] = run;
    }
    __syncthreads();
    for (int off = 1; off < 256; off <<= 1) {
        int u = 0;
        if (s == 0 && t >= off) u = btot[t - off];
        __syncthreads();
        if (s == 0) btot[t] += u;
        __syncthreads();
    }
    if (s == 0) {
        int ex = btot[t] - tot;
        btot[t] = ex;
        if (t < NBKT) bbase[t] = ex;
    }
    __syncthreads();
    if (t < NBKT) {
        int run = btot[t] + segsum[s][t];
        for (int i = 0; i < SEG_LEN; i++) {
            int blk = s * SEG_LEN + i;
            if (blk < P1_BLOCKS) { int idx = blk * NBKT + t; int v = cnt[idx]; cnt[idx] = run; run += v; }
        }
    }
    if (threadIdx.x == 0) bbase[NBKT] = N_EDGES;
}

// ===== Pass 1: bin edges into bucket regions (LDS cursors only) =====
__global__ void bin_edges(const int* __restrict__ src, const int* __restrict__ dst,
                          const float* __restrict__ ew, const int* __restrict__ cnt,
                          int2* __restrict__ binned) {
    __shared__ int lcur[NBKT];
    int t = threadIdx.x;
    if (t < NBKT) lcur[t] = cnt[blockIdx.x * NBKT + t];
    __syncthreads();
    int e0 = blockIdx.x * P1_EDGES;
    for (int k = 0; k < P1_EDGES / 256; k++) {
        int e = e0 + k * 256 + t;
        if (e < N_EDGES) {
            int d = dst[e];
            int b = d >> BSHIFT;
            int pos = atomicAdd(&lcur[b], 1);
            binned[pos] = make_int2(src[e] | ((d & 255) << 16), __float_as_int(ew[e]));
        }
    }
}

// ===== Pass 2: sort each bucket by exact dst, emit row_ptr + packed 4B edges =====
__global__ void sort_bucket(const int* __restrict__ bbase, const int2* __restrict__ binned,
                            unsigned* __restrict__ sorted, int* __restrict__ row_ptr) {
    __shared__ int nh[256];
    __shared__ int scn[256];
    __shared__ int lcur[256];
    int b = blockIdx.x;
    int t = threadIdx.x;
    int beg = bbase[b], end = bbase[b + 1];
    nh[t] = 0;
    __syncthreads();
    for (int e = beg + t; e < end; e += 256)
        atomicAdd(&nh[(binned[e].x >> 16) & 255], 1);
    __syncthreads();
    int v = nh[t];
    scn[t] = v;
    __syncthreads();
    for (int off = 1; off < 256; off <<= 1) {
        int u = (t >= off) ? scn[t - off] : 0;
        __syncthreads();
        scn[t] += u;
        __syncthreads();
    }
    int ex = scn[t] - v;
    int node = (b << BSHIFT) + t;
    if (node < N_NODES) row_ptr[node] = beg + ex;
    __syncthreads();
    nh[t] = ex;
    lcur[t] = 0;
    __syncthreads();
    for (int e = beg + t; e < end; e += 256) {
        int2 p = binned[e];
        int dlow = (p.x >> 16) & 255;
        int pos = beg + nh[dlow] + atomicAdd(&lcur[dlow], 1);
        unsigned hw = (unsigned)__half_as_ushort(__float2half(__int_as_float(p.y)));
        sorted[pos] = (unsigned)(p.x & 0xFFFF) | (hw << 16);
    }
    if (b == 0 && t == 0) row_ptr[N_NODES] = N_EDGES;
}

__device__ __forceinline__ float edge_w(unsigned p) {
    return __half2float(__ushort_as_half((unsigned short)(p >> 16)));
}

// ====== Fused layer 1 -> t2 SLICED layout: t2s[slice][node][8] fp16 ======
#define L1_NPW 2
#define L1_NODES_PER_BLOCK (4 * 4 * L1_NPW)  // 32
__global__ void fused_l1(const int* __restrict__ row_ptr, const unsigned* __restrict__ sorted,
                         const float* __restrict__ x, const float* __restrict__ W1,
                         const float* __restrict__ b1, const float* __restrict__ W2,
                         __half* __restrict__ t2s) {
    __shared__ float w2s[128 * 64];
    __shared__ float hls[4][4][128];
    for (int k = threadIdx.x; k < 128 * 64; k += 256) w2s[k] = W2[k];
    int wave = threadIdx.x >> 6;
    int lane = threadIdx.x & 63;
    float w1a = W1[lane],      w1b = W1[128 + lane];
    float w1c = W1[64 + lane], w1d = W1[192 + lane];
    float b1lo = b1[lane], b1hi = b1[64 + lane];
    __syncthreads();

    int sub = lane >> 4;
    int sl  = lane & 15;
    // sliced store offset for this lane's feature (feat = lane)
    long soff = (long)(lane >> 3) * (N_NODES * 8) + (lane & 7);

    for (int it = 0; it < L1_NPW; it++) {
        int base = blockIdx.x * L1_NODES_PER_BLOCK + wave * (4 * L1_NPW) + it * 4;
        int gnode = base + sub;
        float a0 = 0.f, a1 = 0.f;
        if (gnode < N_NODES) {
            int beg = row_ptr[gnode], end = row_ptr[gnode + 1];
            for (int e = beg + sl; e < end; e += 16) {
                unsigned p = sorted[e];
                float w = edge_w(p);
                float2 xv = ((const float2*)x)[p & 0xFFFF];
                a0 = fmaf(w, xv.x, a0);
                a1 = fmaf(w, xv.y, a1);
            }
        }
#pragma unroll
        for (int off = 1; off < 16; off <<= 1) {
            a0 += __shfl_xor(a0, off);
            a1 += __shfl_xor(a1, off);
        }
#pragma unroll
        for (int n = 0; n < 4; n++) {
            float an0 = __shfl(a0, 16 * n);
            float an1 = __shfl(a1, 16 * n);
            float hlo = fmaxf(fmaf(an0, w1a, fmaf(an1, w1b, b1lo)), 0.f);
            float hhi = fmaxf(fmaf(an0, w1c, fmaf(an1, w1d, b1hi)), 0.f);
            hls[wave][n][lane] = hlo;
            hls[wave][n][64 + lane] = hhi;
        }
        float acc0 = 0.f, acc1 = 0.f, acc2 = 0.f, acc3 = 0.f;
#pragma unroll 4
        for (int k4 = 0; k4 < 32; k4++) {
            float w0 = w2s[(4 * k4 + 0) * 64 + lane];
            float w1 = w2s[(4 * k4 + 1) * 64 + lane];
            float w2 = w2s[(4 * k4 + 2) * 64 + lane];
            float w3 = w2s[(4 * k4 + 3) * 64 + lane];
            float4 h0 = *(const float4*)&hls[wave][0][4 * k4];
            float4 h1 = *(const float4*)&hls[wave][1][4 * k4];
            float4 h2 = *(const float4*)&hls[wave][2][4 * k4];
            float4 h3 = *(const float4*)&hls[wave][3][4 * k4];
            acc0 = fmaf(h0.x, w0, fmaf(h0.y, w1, fmaf(h0.z, w2, fmaf(h0.w, w3, acc0))));
            acc1 = fmaf(h1.x, w0, fmaf(h1.y, w1, fmaf(h1.z, w2, fmaf(h1.w, w3, acc1))));
            acc2 = fmaf(h2.x, w0, fmaf(h2.y, w1, fmaf(h2.z, w2, fmaf(h2.w, w3, acc2))));
            acc3 = fmaf(h3.x, w0, fmaf(h3.y, w1, fmaf(h3.z, w2, fmaf(h3.w, w3, acc3))));
        }
        if (base + 0 < N_NODES) t2s[soff + (long)(base + 0) * 8] = __float2half(acc0);
        if (base + 1 < N_NODES) t2s[soff + (long)(base + 1) * 8] = __float2half(acc1);
        if (base + 2 < N_NODES) t2s[soff + (long)(base + 2) * 8] = __float2half(acc2);
        if (base + 3 < N_NODES) t2s[soff + (long)(base + 3) * 8] = __float2half(acc3);
    }
}

// ====== Layer 2 gather, XCD-sliced: slice = blockIdx&7 -> one XCD owns one 800KB slice ======
// 16 lanes/node, lane=edge; per edge one uint4 (8 fp16 feats). Butterfly over 16 lanes,
// then relu(acc+b2_slice)·W3_slice partial atomically added into t3[node].
__global__ void gather2_sliced(const int* __restrict__ row_ptr, const unsigned* __restrict__ sorted,
                               const __half* __restrict__ t2s, const float* __restrict__ b2,
                               const float* __restrict__ W3, float* __restrict__ t3) {
    int slice = blockIdx.x & 7;
    int chunk = blockIdx.x >> 3;
    int wave = threadIdx.x >> 6;
    int lane = threadIdx.x & 63;
    int sub = lane >> 4;
    int sl  = lane & 15;
    int node = chunk * 16 + wave * 4 + sub;
    if (node >= N_NODES) return;
    const uint4* sb = (const uint4*)(t2s + (long)slice * (N_NODES * 8));
    int beg = row_ptr[node], end = row_ptr[node + 1];
    float a0 = 0.f, a1 = 0.f, a2 = 0.f, a3 = 0.f, a4 = 0.f, a5 = 0.f, a6 = 0.f, a7 = 0.f;
    for (int e = beg + sl; e < end; e += 16) {
        unsigned p = sorted[e];
        float w = edge_w(p);
        uint4 q = sb[p & 0xFFFF];
        float2 f0 = __half22float2(*(const __half2*)&q.x);
        float2 f1 = __half22float2(*(const __half2*)&q.y);
        float2 f2 = __half22float2(*(const __half2*)&q.z);
        float2 f3 = __half22float2(*(const __half2*)&q.w);
        a0 = fmaf(w, f0.x, a0); a1 = fmaf(w, f0.y, a1);
        a2 = fmaf(w, f1.x, a2); a3 = fmaf(w, f1.y, a3);
        a4 = fmaf(w, f2.x, a4); a5 = fmaf(w, f2.y, a5);
        a6 = fmaf(w, f3.x, a6); a7 = fmaf(w, f3.y, a7);
    }
#pragma unroll
    for (int off = 1; off < 16; off <<= 1) {
        a0 += __shfl_xor(a0, off); a1 += __shfl_xor(a1, off);
        a2 += __shfl_xor(a2, off); a3 += __shfl_xor(a3, off);
        a4 += __shfl_xor(a4, off); a5 += __shfl_xor(a5, off);
        a6 += __shfl_xor(a6, off); a7 += __shfl_xor(a7, off);
    }
    if (sl == 0) {
        float4 bA = ((const float4*)(b2 + slice * 8))[0];
        float4 bB = ((const float4*)(b2 + slice * 8))[1];
        float4 wA = ((const float4*)(W3 + slice * 8))[0];
        float4 wB = ((const float4*)(W3 + slice * 8))[1];
        float s = fmaxf(a0 + bA.x, 0.f) * wA.x + fmaxf(a1 + bA.y, 0.f) * wA.y +
                  fmaxf(a2 + bA.z, 0.f) * wA.z + fmaxf(a3 + bA.w, 0.f) * wA.w +
                  fmaxf(a4 + bB.x, 0.f) * wB.x + fmaxf(a5 + bB.y, 0.f) * wB.y +
                  fmaxf(a6 + bB.z, 0.f) * wB.z + fmaxf(a7 + bB.w, 0.f) * wB.w;
        atomicAdd(&t3[node], s);
    }
}

// ====== Layer 3: gather scalar t3 ======
__global__ void gather3(const int* __restrict__ row_ptr, const unsigned* __restrict__ sorted,
                        const float* __restrict__ t3, const float* __restrict__ b3,
                        float* __restrict__ out) {
    int i = blockIdx.x * blockDim.x + threadIdx.x;
    if (i >= N_NODES) return;
    int beg = row_ptr[i], end = row_ptr[i + 1];
    float acc = 0.f;
    for (int e = beg; e < end; e++) {
        unsigned p = sorted[e];
        acc = fmaf(edge_w(p), t3[p & 0xFFFF], acc);
    }
    out[i] = acc + b3[0];
}

extern "C" void kernel_launch(void* const* d_in, const int* in_sizes, int n_in,
                              void* d_out, int out_size, void* d_ws, size_t ws_size,
                              hipStream_t stream) {
    const float* x  = (const float*)d_in[0];
    const int*   ei = (const int*)d_in[1];     // [2, E]
    const float* ew = (const float*)d_in[2];
    const float* W1 = (const float*)d_in[3];
    const float* b1 = (const float*)d_in[4];
    const float* W2 = (const float*)d_in[5];
    const float* b2 = (const float*)d_in[6];
    const float* W3 = (const float*)d_in[7];
    const float* b3 = (const float*)d_in[8];
    float* out = (float*)d_out;

    const int* src = ei;
    const int* dst = ei + N_EDGES;

    // workspace layout
    char* p = (char*)d_ws;
    int*  cnt     = (int*)p;            p += P1_BLOCKS * NBKT * sizeof(int);
    int*  bbase   = (int*)p;            p += (NBKT + 1) * sizeof(int);
    int*  row_ptr = (int*)p;            p += (N_NODES + 1) * sizeof(int);
    p = (char*)(((uintptr_t)p + 15) & ~(uintptr_t)15);
    int2* binned      = (int2*)p;       p += N_EDGES * sizeof(int2);          // 6.4 MB
    unsigned* sorted  = (unsigned*)p;   p += N_EDGES * sizeof(unsigned);      // 3.2 MB
    __half* t2s   = (__half*)p;         p += 8L * N_NODES * 8 * sizeof(__half); // 6.4 MB
    float* t3     = (float*)p;          p += N_NODES * sizeof(float);

    // CSR build: count matrix -> cursor scan -> bin -> per-bucket sort
    count_kernel<<<P1_BLOCKS, 256, 0, stream>>>(dst, cnt);
    scan_matrix<<<1, 1024, 0, stream>>>(cnt, bbase);
    bin_edges<<<P1_BLOCKS, 256, 0, stream>>>(src, dst, ew, cnt, binned);
    sort_bucket<<<NBKT, 256, 0, stream>>>(bbase, binned, sorted, row_ptr);

    // Layer 1 (fused gather + dense 2->128 + relu + dense 128->64, sliced fp16 out)
    fused_l1<<<(N_NODES + L1_NODES_PER_BLOCK - 1) / L1_NODES_PER_BLOCK, 256, 0, stream>>>(
        row_ptr, sorted, x, W1, b1, W2, t2s);

    // Layer 2 gather + fused layer-3 projection (XCD-sliced)
    hipMemsetAsync(t3, 0, N_NODES * sizeof(float), stream);
    gather2_sliced<<<((N_NODES + 15) / 16) * 8, 256, 0, stream>>>(row_ptr, sorted, t2s, b2, W3, t3);

    // Layer 3
    gather3<<<(N_NODES + 255) / 256, 256, 0, stream>>>(row_ptr, sorted, t3, b3, out);
}